// Round 3
// baseline (504.859 us; speedup 1.0000x reference)
//
#include <hip/hip_runtime.h>
#include <stdint.h>

#define NBATCH 4
#define TQ 2048
#define TKK 8192
#define DM 1024
#define HDIM 64
#define LLEN 512

typedef __bf16 bf16;
typedef __attribute__((ext_vector_type(4))) float f32x4;
typedef __attribute__((ext_vector_type(8))) __bf16 bf16x8;
typedef __attribute__((ext_vector_type(4))) __bf16 bf16x4;

typedef const __attribute__((address_space(1))) void* gas1_t;
typedef __attribute__((address_space(3))) void* las3_t;

__device__ __forceinline__ void gload_lds16(const void* g, void* l) {
  __builtin_amdgcn_global_load_lds((gas1_t)(uintptr_t)g, (las3_t)(uint32_t)(uintptr_t)l, 16, 0, 0);
}

__device__ __forceinline__ void cast4(const float* __restrict__ src, bf16* __restrict__ dst, int i) {
  float4 v = ((const float4*)src)[i];
  bf16x4 o;
  o[0] = (bf16)v.x; o[1] = (bf16)v.y; o[2] = (bf16)v.z; o[3] = (bf16)v.w;
  ((bf16x4*)dst)[i] = o;
}

// ---------------- merged prep: all casts + mask in one launch ----------------
__global__ void prep_kernel(const float* __restrict__ q,
                            const float* __restrict__ wq, const float* __restrict__ wk,
                            const float* __restrict__ wv, const float* __restrict__ wo,
                            const int* __restrict__ sm,
                            bf16* __restrict__ QB, bf16* __restrict__ WQ, bf16* __restrict__ WK,
                            bf16* __restrict__ WV, bf16* __restrict__ WO, float* __restrict__ MF) {
  int tid = blockIdx.x * blockDim.x + threadIdx.x;
  int stride = gridDim.x * blockDim.x;  // 2048*256 = 524288
  for (int i = tid; i < 2097152; i += stride) cast4(q, QB, i);
  for (int i = tid; i < 262144; i += stride) cast4(wq, WQ, i);
  for (int i = tid; i < 262144; i += stride) cast4(wk, WK, i);
  for (int i = tid; i < 262144; i += stride) cast4(wv, WV, i);
  for (int i = tid; i < 262144; i += stride) cast4(wo, WO, i);
  for (int i = tid; i < 32768; i += stride) {
    int bh = i >> 9, l = i & 511;
    int b = bh >> 4, h = bh & 15;
    MF[i] = sm[b * TKK + h + 16 * l] ? 1.0f : 0.0f;
  }
}

// ---------------- GEMM-BT + bias (+scale), m97 structure, XCD-swizzled ----------------
// C[m,n] = (sum_k A[m,k]*B[n,k] + bias[n]) * scale ; lda=ldb=ldc=1024
// 128x128 tile, BK=64, 4 waves (2x2), global_load_lds staging (linear LDS). 1D grid 512.
template<bool OUT_BF16>
__global__ __launch_bounds__(256) void gemm_bt_bias(
    const bf16* __restrict__ A, const bf16* __restrict__ Bm,
    const float* __restrict__ bias, void* __restrict__ Cout, float scale) {
  __shared__ bf16 As[128 * 64];
  __shared__ bf16 Bs[128 * 64];
  const int t = threadIdx.x;
  const int lane = t & 63, w = t >> 6;
  const int wm = w >> 1, wn = w & 1;
  // XCD swizzle: 512 blocks, cpx=64; XCD x owns logical [x*64, x*64+64) = 8 mtiles x 8 ntiles
  const int bid = blockIdx.x;
  const int swz = (bid & 7) * 64 + (bid >> 3);
  const int m0 = (swz >> 3) * 128, n0 = (swz & 7) * 128;
  const int c = lane & 15, g = lane >> 4;
  f32x4 acc[4][4] = {};
  for (int k0 = 0; k0 < DM; k0 += 64) {
    __syncthreads();
    #pragma unroll
    for (int i = 0; i < 4; ++i) {
      int chunk = i * 256 + t;
      int row = chunk >> 3, blk = chunk & 7;
      gload_lds16(A + (size_t)(m0 + row) * DM + k0 + blk * 8, As + chunk * 8);
      gload_lds16(Bm + (size_t)(n0 + row) * DM + k0 + blk * 8, Bs + chunk * 8);
    }
    __syncthreads();
    #pragma unroll
    for (int kk = 0; kk < 2; ++kk) {
      bf16x8 af[4], bfr[4];
      #pragma unroll
      for (int f = 0; f < 4; ++f)
        af[f] = *(const bf16x8*)(As + (wm * 64 + f * 16 + c) * 64 + kk * 32 + g * 8);
      #pragma unroll
      for (int f = 0; f < 4; ++f)
        bfr[f] = *(const bf16x8*)(Bs + (wn * 64 + f * 16 + c) * 64 + kk * 32 + g * 8);
      #pragma unroll
      for (int mi = 0; mi < 4; ++mi)
        #pragma unroll
        for (int ni = 0; ni < 4; ++ni)
          acc[mi][ni] = __builtin_amdgcn_mfma_f32_16x16x32_bf16(af[mi], bfr[ni], acc[mi][ni], 0, 0, 0);
    }
  }
  #pragma unroll
  for (int ni = 0; ni < 4; ++ni) {
    int n = n0 + wn * 64 + ni * 16 + c;
    float bv = bias[n];
    #pragma unroll
    for (int mi = 0; mi < 4; ++mi) {
      int m = m0 + wm * 64 + mi * 16 + g * 4;
      #pragma unroll
      for (int j = 0; j < 4; ++j) {
        float vv = (acc[mi][ni][j] + bv) * scale;
        if (OUT_BF16) ((bf16*)Cout)[(size_t)(m + j) * DM + n] = (bf16)vv;
        else          ((float*)Cout)[(size_t)(m + j) * DM + n] = vv;
      }
    }
  }
}

// ---------------- fused sliced K/V projection ----------------
// Per (b,h): C[l,d] = sum_k X[b, h+16*l, k] * W[h*64+d, k] + bias[h*64+d]
// iz==0: K-hat -> Out[bh][l][d].  iz==1: V^T -> Out[bh][d][l].
// BM=64 tile, BK=64; 1024 blocks (4/CU); reg-staged fp32->bf16, XOR-swizzled LDS.
__global__ __launch_bounds__(256) void kv_proj_fused(
    const float* __restrict__ Xk, const float* __restrict__ Xv,
    const bf16* __restrict__ WK, const bf16* __restrict__ WV,
    const float* __restrict__ bk, const float* __restrict__ bv,
    bf16* __restrict__ KH, bf16* __restrict__ VTT) {
  __shared__ bf16 As[64 * 64];
  __shared__ bf16 Bs[64 * 64];
  const int t = threadIdx.x, lane = t & 63, w = t >> 6;
  const int wm = w >> 1, wn = w & 1;
  // 1024 blocks; logical = iz*512 + bh*8 + ltile; XCD x owns 128 logical (one iz, 16 bh)
  const int bid = blockIdx.x;
  const int swz = (bid & 7) * 128 + (bid >> 3);
  const int iz = swz >> 9;
  const int bh = (swz >> 3) & 63;
  const int ltile = swz & 7;
  const int b = bh >> 4, h = bh & 15;
  const int l0 = ltile * 64;
  const float* __restrict__ X = iz ? Xv : Xk;
  const bf16* __restrict__ W = iz ? WV : WK;
  const float* __restrict__ bias = iz ? bv : bk;
  const int c = lane & 15, g = lane >> 4;
  f32x4 acc[2][2] = {};
  for (int k0 = 0; k0 < DM; k0 += 64) {
    __syncthreads();
    #pragma unroll
    for (int i = 0; i < 4; ++i) {  // A: 64x64 fp32 = 1024 float4 chunks
      int chunk = i * 256 + t;
      int row = chunk >> 4, q4 = chunk & 15;
      float4 vv = *(const float4*)(X + ((size_t)b * TKK + h + 16 * (l0 + row)) * DM + k0 + q4 * 4);
      bf16x4 o;
      o[0] = (bf16)vv.x; o[1] = (bf16)vv.y; o[2] = (bf16)vv.z; o[3] = (bf16)vv.w;
      uint32_t byte = (uint32_t)(row * 128 + q4 * 8) ^ (uint32_t)((row & 7) << 4);
      *(bf16x4*)((char*)As + byte) = o;
    }
    #pragma unroll
    for (int i = 0; i < 2; ++i) {  // B: 64x64 bf16 = 512 16B chunks
      int chunk = i * 256 + t;
      int row = chunk >> 3, blk = chunk & 7;
      uint4 vv = *(const uint4*)(W + (size_t)(h * 64 + row) * DM + k0 + blk * 8);
      uint32_t byte = (uint32_t)(row * 128 + blk * 16) ^ (uint32_t)((row & 7) << 4);
      *(uint4*)((char*)Bs + byte) = vv;
    }
    __syncthreads();
    #pragma unroll
    for (int kk = 0; kk < 2; ++kk) {
      bf16x8 af[2], bfr[2];
      #pragma unroll
      for (int f = 0; f < 2; ++f) {
        int row = wm * 32 + f * 16 + c;
        uint32_t byte = (uint32_t)(row * 128 + (kk * 32 + g * 8) * 2) ^ (uint32_t)((row & 7) << 4);
        af[f] = *(const bf16x8*)((char*)As + byte);
      }
      #pragma unroll
      for (int f = 0; f < 2; ++f) {
        int row = wn * 32 + f * 16 + c;
        uint32_t byte = (uint32_t)(row * 128 + (kk * 32 + g * 8) * 2) ^ (uint32_t)((row & 7) << 4);
        bfr[f] = *(const bf16x8*)((char*)Bs + byte);
      }
      #pragma unroll
      for (int mi = 0; mi < 2; ++mi)
        #pragma unroll
        for (int ni = 0; ni < 2; ++ni)
          acc[mi][ni] = __builtin_amdgcn_mfma_f32_16x16x32_bf16(af[mi], bfr[ni], acc[mi][ni], 0, 0, 0);
    }
  }
  #pragma unroll
  for (int ni = 0; ni < 2; ++ni) {
    int n = wn * 32 + ni * 16 + c;  // d in [0,64)
    float bvv = bias[h * 64 + n];
    #pragma unroll
    for (int mi = 0; mi < 2; ++mi) {
      int m = wm * 32 + mi * 16 + g * 4;  // l_local
      if (iz == 0) {
        #pragma unroll
        for (int j = 0; j < 4; ++j)
          KH[((size_t)bh * LLEN + l0 + m + j) * 64 + n] = (bf16)(acc[mi][ni][j] + bvv);
      } else {
        bf16x4 o;
        #pragma unroll
        for (int j = 0; j < 4; ++j) o[j] = (bf16)(acc[mi][ni][j] + bvv);
        *(bf16x4*)(VTT + ((size_t)bh * 64 + n) * LLEN + l0 + m) = o;
      }
    }
  }
}

// ---------------- flash attention over the strided-gathered KV ----------------
__device__ __forceinline__ void stage_kv(const bf16* __restrict__ KH, const bf16* __restrict__ VT,
                                         bf16* Ks, bf16* Vs, int bh, int lt, int t) {
  #pragma unroll
  for (int i = 0; i < 4; ++i) {  // K tile: 128(l) x 64(d) bf16
    int chunk = i * 256 + t, row = chunk >> 3, blk = chunk & 7;
    uint4 v = *(const uint4*)(KH + ((size_t)bh * LLEN + lt * 128 + row) * 64 + blk * 8);
    uint32_t byte = (uint32_t)(row * 128 + blk * 16) ^ (uint32_t)((row & 7) << 4);
    *(uint4*)((char*)Ks + byte) = v;
  }
  #pragma unroll
  for (int i = 0; i < 4; ++i) {  // V^T tile: 64(d) x 128(l) bf16
    int chunk = i * 256 + t, row = chunk >> 4, blk = chunk & 15;
    uint4 v = *(const uint4*)(VT + ((size_t)bh * 64 + row) * LLEN + lt * 128 + blk * 8);
    uint32_t byte = (uint32_t)(row * 256 + blk * 16) ^ (uint32_t)((row & 7) << 4);
    *(uint4*)((char*)Vs + byte) = v;
  }
}

__global__ __launch_bounds__(256) void attn_kernel(
    const bf16* __restrict__ Qp, const bf16* __restrict__ KH, const bf16* __restrict__ VT,
    const float* __restrict__ maskf, bf16* __restrict__ AO) {
  __shared__ bf16 Qs[128 * 64];
  __shared__ bf16 Ks[128 * 64];
  __shared__ bf16 Vs[64 * 128];
  const int t = threadIdx.x, lane = t & 63, w = t >> 6;
  // 1024 blocks; logical = bh*16 + qtile; XCD x owns 128 logical = 8 bh, all q-tiles
  const int bid = blockIdx.x;
  const int swz = (bid & 7) * 128 + (bid >> 3);
  const int bh = swz >> 4, b = bh >> 4, h = bh & 15;
  const int q0 = (swz & 15) * 128;
  const int c = lane & 15, g = lane >> 4;

  #pragma unroll
  for (int i = 0; i < 4; ++i) {  // stage Q tile: 128(q) x 64(d), 1/8-scaled upstream
    int chunk = i * 256 + t, row = chunk >> 3, blk = chunk & 7;
    uint4 v = *(const uint4*)(Qp + ((size_t)(b * TQ + q0 + row)) * DM + h * 64 + blk * 8);
    uint32_t byte = (uint32_t)(row * 128 + blk * 16) ^ (uint32_t)((row & 7) << 4);
    *(uint4*)((char*)Qs + byte) = v;
  }
  stage_kv(KH, VT, Ks, Vs, bh, 0, t);
  __syncthreads();

  // hoist Q fragments (B-operand of S^T = mfma(K, Q)): lane holds q = w*32 + nf*16 + c
  bf16x8 bq[2][2];
  #pragma unroll
  for (int nf = 0; nf < 2; ++nf)
    #pragma unroll
    for (int kk = 0; kk < 2; ++kk) {
      int row = w * 32 + nf * 16 + c;
      uint32_t byte = (uint32_t)(row * 128 + (kk * 32 + g * 8) * 2) ^ (uint32_t)((row & 7) << 4);
      bq[nf][kk] = *(const bf16x8*)((char*)Qs + byte);
    }

  float m_run[2] = {-1e30f, -1e30f};
  float l_run[2] = {0.0f, 0.0f};
  f32x4 acc_o[4][2] = {};  // O^T: m=d (4 frags), n=q (2 frags)

  #pragma unroll 1
  for (int lt = 0; lt < 4; ++lt) {
    // S^T tile: C[m=l(128), n=q(32)]
    f32x4 s[8][2] = {};
    #pragma unroll
    for (int kk = 0; kk < 2; ++kk) {
      bf16x8 ak[8];
      #pragma unroll
      for (int mf = 0; mf < 8; ++mf) {
        int row = mf * 16 + c;
        uint32_t byte = (uint32_t)(row * 128 + (kk * 32 + g * 8) * 2) ^ (uint32_t)((row & 7) << 4);
        ak[mf] = *(const bf16x8*)((char*)Ks + byte);
      }
      __builtin_amdgcn_s_setprio(1);
      #pragma unroll
      for (int mf = 0; mf < 8; ++mf)
        #pragma unroll
        for (int nf = 0; nf < 2; ++nf)
          s[mf][nf] = __builtin_amdgcn_mfma_f32_16x16x32_bf16(ak[mf], bq[nf][kk], s[mf][nf], 0, 0, 0);
      __builtin_amdgcn_s_setprio(0);
    }
    // online softmax: lane holds, for q = w*32+nf*16+c, l-values {16*mf + 4*g + j}
    #pragma unroll
    for (int nf = 0; nf < 2; ++nf) {
      float mnew = m_run[nf];
      #pragma unroll
      for (int mf = 0; mf < 8; ++mf)
        #pragma unroll
        for (int j = 0; j < 4; ++j)
          mnew = fmaxf(mnew, s[mf][nf][j]);
      mnew = fmaxf(mnew, __shfl_xor(mnew, 16));
      mnew = fmaxf(mnew, __shfl_xor(mnew, 32));
      float fs = exp2f((m_run[nf] - mnew) * 1.44269504f);
      m_run[nf] = mnew;
      float rs = 0.0f;
      #pragma unroll
      for (int mf = 0; mf < 8; ++mf) {
        float4 mk = *(const float4*)(maskf + (size_t)bh * LLEN + lt * 128 + mf * 16 + 4 * g);
        #pragma unroll
        for (int j = 0; j < 4; ++j) {
          float p = exp2f((s[mf][nf][j] - mnew) * 1.44269504f) * ((const float*)&mk)[j];
          s[mf][nf][j] = p;
          rs += p;
        }
      }
      rs += __shfl_xor(rs, 16);
      rs += __shfl_xor(rs, 32);
      l_run[nf] = l_run[nf] * fs + rs;
      #pragma unroll
      for (int mf = 0; mf < 4; ++mf) acc_o[mf][nf] *= fs;
    }
    // PV: O^T += V^T * P, bijective k-slot permutation applied to both operands
    #pragma unroll
    for (int kk = 0; kk < 4; ++kk) {
      bf16x8 pb[2];
      #pragma unroll
      for (int nf = 0; nf < 2; ++nf)
        #pragma unroll
        for (int s8 = 0; s8 < 8; ++s8)
          pb[nf][s8] = (bf16)s[kk * 2 + (s8 >> 2)][nf][s8 & 3];
      #pragma unroll
      for (int mf = 0; mf < 4; ++mf) {
        int d = mf * 16 + c;
        uint32_t base = (uint32_t)(d * 256 + (kk * 32 + g * 4) * 2);
        uint32_t swzb = (uint32_t)((d & 7) << 4);
        bf16x4 lo = *(const bf16x4*)((char*)Vs + (base ^ swzb));
        bf16x4 hi = *(const bf16x4*)((char*)Vs + ((base + 32) ^ swzb));
        bf16x8 av = __builtin_shufflevector(lo, hi, 0, 1, 2, 3, 4, 5, 6, 7);
        __builtin_amdgcn_s_setprio(1);
        #pragma unroll
        for (int nf = 0; nf < 2; ++nf)
          acc_o[mf][nf] = __builtin_amdgcn_mfma_f32_16x16x32_bf16(av, pb[nf], acc_o[mf][nf], 0, 0, 0);
        __builtin_amdgcn_s_setprio(0);
      }
    }
    if (lt < 3) {
      __syncthreads();
      stage_kv(KH, VT, Ks, Vs, bh, lt + 1, t);
      __syncthreads();
    }
  }
  // epilogue: divide by row sum, write AO[b*TQ+q][h*64+d]
  #pragma unroll
  for (int nf = 0; nf < 2; ++nf) {
    float inv = 1.0f / l_run[nf];
    int qq = q0 + w * 32 + nf * 16 + c;
    #pragma unroll
    for (int mf = 0; mf < 4; ++mf) {
      bf16x4 o;
      #pragma unroll
      for (int j = 0; j < 4; ++j) o[j] = (bf16)(acc_o[mf][nf][j] * inv);
      *(bf16x4*)(AO + ((size_t)(b * TQ + qq)) * DM + h * 64 + mf * 16 + 4 * g) = o;
    }
  }
}

extern "C" void kernel_launch(void* const* d_in, const int* in_sizes, int n_in,
                              void* d_out, int out_size, void* d_ws, size_t ws_size,
                              hipStream_t stream) {
  const float* q   = (const float*)d_in[0];
  const float* k   = (const float*)d_in[1];
  const float* v   = (const float*)d_in[2];
  const int*  smk  = (const int*)d_in[3];
  const float* w_q = (const float*)d_in[4];
  const float* b_q = (const float*)d_in[5];
  const float* w_k = (const float*)d_in[6];
  const float* b_k = (const float*)d_in[7];
  const float* w_v = (const float*)d_in[8];
  const float* b_v = (const float*)d_in[9];
  const float* w_o = (const float*)d_in[10];
  const float* b_o = (const float*)d_in[11];
  float* out = (float*)d_out;

  // workspace layout (bf16 elements): 4 weights | q_bf16 | Q_proj | K_hat | V^T | attn_out | maskf
  bf16* WS  = (bf16*)d_ws;
  bf16* WQ  = WS;
  bf16* WK  = WQ + (1u << 20);
  bf16* WV  = WK + (1u << 20);
  bf16* WO  = WV + (1u << 20);
  bf16* QB  = WO + (1u << 20);
  bf16* QP  = QB + (8u << 20);
  bf16* KH  = QP + (8u << 20);
  bf16* VTT = KH + (2u << 20);
  bf16* AO  = VTT + (2u << 20);
  float* MF = (float*)(AO + (8u << 20));  // total ~64.1 MB

  prep_kernel<<<2048, 256, 0, stream>>>(q, w_q, w_k, w_v, w_o, smk, QB, WQ, WK, WV, WO, MF);
  // Q = (q @ w_q^T + b_q) * 0.125  (attention scale folded in)
  gemm_bt_bias<true><<<512, 256, 0, stream>>>(QB, WQ, b_q, QP, 0.125f);
  // sliced K/V projections (only the consumed 1/16), fused K+V, 1024 blocks
  kv_proj_fused<<<1024, 256, 0, stream>>>(k, v, WK, WV, b_k, b_v, KH, VTT);
  // flash attention per (q-tile, b*h)
  attn_kernel<<<1024, 256, 0, stream>>>(QP, KH, VTT, MF, AO);
  // final projection to fp32 output
  gemm_bt_bias<false><<<512, 256, 0, stream>>>(AO, WO, b_o, out, 1.0f);
}

// Round 6
// 498.499 us; speedup vs baseline: 1.0128x; 1.0128x over previous
//
#include <hip/hip_runtime.h>
#include <stdint.h>

#define NBATCH 4
#define TQ 2048
#define TKK 8192
#define DM 1024
#define HDIM 64
#define LLEN 512

typedef __bf16 bf16;
typedef __attribute__((ext_vector_type(4))) float f32x4;
typedef __attribute__((ext_vector_type(8))) __bf16 bf16x8;
typedef __attribute__((ext_vector_type(4))) __bf16 bf16x4;

typedef const __attribute__((address_space(1))) void* gas1_t;
typedef __attribute__((address_space(3))) void* las3_t;

__device__ __forceinline__ void gload_lds16(const void* g, void* l) {
  __builtin_amdgcn_global_load_lds((gas1_t)(uintptr_t)g, (las3_t)(uint32_t)(uintptr_t)l, 16, 0, 0);
}

__device__ __forceinline__ void cast4(const float* __restrict__ src, bf16* __restrict__ dst, int i) {
  float4 v = ((const float4*)src)[i];
  bf16x4 o;
  o[0] = (bf16)v.x; o[1] = (bf16)v.y; o[2] = (bf16)v.z; o[3] = (bf16)v.w;
  ((bf16x4*)dst)[i] = o;
}

// ---------------- merged prep: all casts + mask in one launch ----------------
__global__ void prep_kernel(const float* __restrict__ q,
                            const float* __restrict__ wq, const float* __restrict__ wk,
                            const float* __restrict__ wv, const float* __restrict__ wo,
                            const int* __restrict__ sm,
                            bf16* __restrict__ QB, bf16* __restrict__ WQ, bf16* __restrict__ WK,
                            bf16* __restrict__ WV, bf16* __restrict__ WO, float* __restrict__ MF) {
  int tid = blockIdx.x * blockDim.x + threadIdx.x;
  int stride = gridDim.x * blockDim.x;
  for (int i = tid; i < 2097152; i += stride) cast4(q, QB, i);
  for (int i = tid; i < 262144; i += stride) cast4(wq, WQ, i);
  for (int i = tid; i < 262144; i += stride) cast4(wk, WK, i);
  for (int i = tid; i < 262144; i += stride) cast4(wv, WV, i);
  for (int i = tid; i < 262144; i += stride) cast4(wo, WO, i);
  for (int i = tid; i < 32768; i += stride) {
    int bh = i >> 9, l = i & 511;
    int b = bh >> 4, h = bh & 15;
    MF[i] = sm[b * TKK + h + 16 * l] ? 1.0f : 0.0f;
  }
}

// ---------------- GEMM-BT + bias (+scale), m97 structure, XCD-swizzled ----------------
template<bool OUT_BF16>
__global__ __launch_bounds__(256) void gemm_bt_bias(
    const bf16* __restrict__ A, const bf16* __restrict__ Bm,
    const float* __restrict__ bias, void* __restrict__ Cout, float scale) {
  __shared__ bf16 As[128 * 64];
  __shared__ bf16 Bs[128 * 64];
  const int t = threadIdx.x;
  const int lane = t & 63, w = t >> 6;
  const int wm = w >> 1, wn = w & 1;
  const int bid = blockIdx.x;
  const int swz = (bid & 7) * 64 + (bid >> 3);
  const int m0 = (swz >> 3) * 128, n0 = (swz & 7) * 128;
  const int c = lane & 15, g = lane >> 4;
  f32x4 acc[4][4] = {};
  for (int k0 = 0; k0 < DM; k0 += 64) {
    __syncthreads();
    #pragma unroll
    for (int i = 0; i < 4; ++i) {
      int chunk = i * 256 + t;
      int row = chunk >> 3, blk = chunk & 7;
      gload_lds16(A + (size_t)(m0 + row) * DM + k0 + blk * 8, As + chunk * 8);
      gload_lds16(Bm + (size_t)(n0 + row) * DM + k0 + blk * 8, Bs + chunk * 8);
    }
    __syncthreads();
    #pragma unroll
    for (int kk = 0; kk < 2; ++kk) {
      bf16x8 af[4], bfr[4];
      #pragma unroll
      for (int f = 0; f < 4; ++f)
        af[f] = *(const bf16x8*)(As + (wm * 64 + f * 16 + c) * 64 + kk * 32 + g * 8);
      #pragma unroll
      for (int f = 0; f < 4; ++f)
        bfr[f] = *(const bf16x8*)(Bs + (wn * 64 + f * 16 + c) * 64 + kk * 32 + g * 8);
      #pragma unroll
      for (int mi = 0; mi < 4; ++mi)
        #pragma unroll
        for (int ni = 0; ni < 4; ++ni)
          acc[mi][ni] = __builtin_amdgcn_mfma_f32_16x16x32_bf16(af[mi], bfr[ni], acc[mi][ni], 0, 0, 0);
    }
  }
  #pragma unroll
  for (int ni = 0; ni < 4; ++ni) {
    int n = n0 + wn * 64 + ni * 16 + c;
    float bv = bias[n];
    #pragma unroll
    for (int mi = 0; mi < 4; ++mi) {
      int m = m0 + wm * 64 + mi * 16 + g * 4;
      #pragma unroll
      for (int j = 0; j < 4; ++j) {
        float vv = (acc[mi][ni][j] + bv) * scale;
        if (OUT_BF16) ((bf16*)Cout)[(size_t)(m + j) * DM + n] = (bf16)vv;
        else          ((float*)Cout)[(size_t)(m + j) * DM + n] = vv;
      }
    }
  }
}

// ---------------- sliced K/V projection, v2: full-K row staging ----------------
// Per (b,h): C[l,d] = sum_k X[b, h+16*l, k] * W[h*64+d, k] + bias[h*64+d]
// BM=16 l-rows, BK=1024 (whole row staged once, one contiguous 4KB read per row).
// A: LDS (32KB, XOR-swizzled). B: direct global->reg (W is L2-resident per XCD).
// iz==0: K-hat -> KH[bh][l][d].  iz==1: V^T -> VTT[bh][d][l].
__global__ __launch_bounds__(256) void kv_proj2(
    const float* __restrict__ Xk, const float* __restrict__ Xv,
    const bf16* __restrict__ WK, const bf16* __restrict__ WV,
    const float* __restrict__ bk, const float* __restrict__ bv,
    bf16* __restrict__ KH, bf16* __restrict__ VTT) {
  __shared__ bf16 As[16 * 1024];  // 32KB
  const int t = threadIdx.x, lane = t & 63, w = t >> 6;
  // 4096 blocks; logical = iz*2048 + bh*32 + ltile; XCD x owns 512 logical (one iz, 16 bh)
  const int bid = blockIdx.x;
  const int swz = (bid & 7) * 512 + (bid >> 3);
  const int iz = swz >> 11;
  const int bh = (swz >> 5) & 63;
  const int l0 = (swz & 31) * 16;
  const int b = bh >> 4, h = bh & 15;
  const float* __restrict__ X = iz ? Xv : Xk;
  const bf16* __restrict__ W = iz ? WV : WK;
  const float* __restrict__ bias = iz ? bv : bk;
  const int c = lane & 15, g = lane >> 4;

  // stage 16 X-rows, full K, cast fp32->bf16; one fully-coalesced 4KB row per iter
  #pragma unroll
  for (int r = 0; r < 16; ++r) {
    float4 vv = *(const float4*)(X + ((size_t)b * TKK + h + 16 * (l0 + r)) * DM + t * 4);
    bf16x4 o;
    o[0] = (bf16)vv.x; o[1] = (bf16)vv.y; o[2] = (bf16)vv.z; o[3] = (bf16)vv.w;
    uint32_t byte = (uint32_t)(r * 2048 + t * 8) ^ (uint32_t)((r & 7) << 4);
    *(bf16x4*)((char*)As + byte) = o;
  }
  __syncthreads();

  // compute: wave w owns d-block w*16..w*16+15; lane's B row is W[h*64 + w*16 + c]
  const bf16* __restrict__ Wb = W + (size_t)(h * 64 + w * 16 + c) * DM;
  f32x4 acc = {};
  #pragma unroll
  for (int ks = 0; ks < 32; ++ks) {
    int k0 = ks * 32;
    uint32_t byte = (uint32_t)(c * 2048 + (k0 + g * 8) * 2) ^ (uint32_t)((c & 7) << 4);
    bf16x8 a = *(const bf16x8*)((char*)As + byte);
    bf16x8 bfrag = *(const bf16x8*)(Wb + k0 + g * 8);
    acc = __builtin_amdgcn_mfma_f32_16x16x32_bf16(a, bfrag, acc, 0, 0, 0);
  }
  // D: l = l0 + 4g + j, d = w*16 + c
  const int d = w * 16 + c;
  const float bvv = bias[h * 64 + d];
  if (iz == 0) {
    #pragma unroll
    for (int j = 0; j < 4; ++j)
      KH[((size_t)bh * LLEN + l0 + 4 * g + j) * 64 + d] = (bf16)(acc[j] + bvv);
  } else {
    bf16x4 o;
    #pragma unroll
    for (int j = 0; j < 4; ++j) o[j] = (bf16)(acc[j] + bvv);
    *(bf16x4*)(VTT + ((size_t)bh * 64 + d) * LLEN + l0 + 4 * g) = o;
  }
}

// ---------------- flash attention over the strided-gathered KV ----------------
__device__ __forceinline__ void stage_kv(const bf16* __restrict__ KH, const bf16* __restrict__ VT,
                                         bf16* Ks, bf16* Vs, int bh, int lt, int t) {
  #pragma unroll
  for (int i = 0; i < 4; ++i) {  // K tile: 128(l) x 64(d) bf16
    int chunk = i * 256 + t, row = chunk >> 3, blk = chunk & 7;
    uint4 v = *(const uint4*)(KH + ((size_t)bh * LLEN + lt * 128 + row) * 64 + blk * 8);
    uint32_t byte = (uint32_t)(row * 128 + blk * 16) ^ (uint32_t)((row & 7) << 4);
    *(uint4*)((char*)Ks + byte) = v;
  }
  #pragma unroll
  for (int i = 0; i < 4; ++i) {  // V^T tile: 64(d) x 128(l) bf16
    int chunk = i * 256 + t, row = chunk >> 4, blk = chunk & 15;
    uint4 v = *(const uint4*)(VT + ((size_t)bh * 64 + row) * LLEN + lt * 128 + blk * 8);
    uint32_t byte = (uint32_t)(row * 256 + blk * 16) ^ (uint32_t)((row & 7) << 4);
    *(uint4*)((char*)Vs + byte) = v;
  }
}

__global__ __launch_bounds__(256) void attn_kernel(
    const bf16* __restrict__ Qp, const bf16* __restrict__ KH, const bf16* __restrict__ VT,
    const float* __restrict__ maskf, bf16* __restrict__ AO) {
  __shared__ bf16 Qs[128 * 64];
  __shared__ bf16 Ks[128 * 64];
  __shared__ bf16 Vs[64 * 128];
  const int t = threadIdx.x, lane = t & 63, w = t >> 6;
  const int bid = blockIdx.x;
  const int swz = (bid & 7) * 128 + (bid >> 3);
  const int bh = swz >> 4, b = bh >> 4, h = bh & 15;
  const int q0 = (swz & 15) * 128;
  const int c = lane & 15, g = lane >> 4;

  #pragma unroll
  for (int i = 0; i < 4; ++i) {  // stage Q tile: 128(q) x 64(d), 1/8-scaled upstream
    int chunk = i * 256 + t, row = chunk >> 3, blk = chunk & 7;
    uint4 v = *(const uint4*)(Qp + ((size_t)(b * TQ + q0 + row)) * DM + h * 64 + blk * 8);
    uint32_t byte = (uint32_t)(row * 128 + blk * 16) ^ (uint32_t)((row & 7) << 4);
    *(uint4*)((char*)Qs + byte) = v;
  }
  stage_kv(KH, VT, Ks, Vs, bh, 0, t);
  __syncthreads();

  bf16x8 bq[2][2];
  #pragma unroll
  for (int nf = 0; nf < 2; ++nf)
    #pragma unroll
    for (int kk = 0; kk < 2; ++kk) {
      int row = w * 32 + nf * 16 + c;
      uint32_t byte = (uint32_t)(row * 128 + (kk * 32 + g * 8) * 2) ^ (uint32_t)((row & 7) << 4);
      bq[nf][kk] = *(const bf16x8*)((char*)Qs + byte);
    }

  float m_run[2] = {-1e30f, -1e30f};
  float l_run[2] = {0.0f, 0.0f};
  f32x4 acc_o[4][2] = {};

  #pragma unroll 1
  for (int lt = 0; lt < 4; ++lt) {
    f32x4 s[8][2] = {};
    #pragma unroll
    for (int kk = 0; kk < 2; ++kk) {
      bf16x8 ak[8];
      #pragma unroll
      for (int mf = 0; mf < 8; ++mf) {
        int row = mf * 16 + c;
        uint32_t byte = (uint32_t)(row * 128 + (kk * 32 + g * 8) * 2) ^ (uint32_t)((row & 7) << 4);
        ak[mf] = *(const bf16x8*)((char*)Ks + byte);
      }
      __builtin_amdgcn_s_setprio(1);
      #pragma unroll
      for (int mf = 0; mf < 8; ++mf)
        #pragma unroll
        for (int nf = 0; nf < 2; ++nf)
          s[mf][nf] = __builtin_amdgcn_mfma_f32_16x16x32_bf16(ak[mf], bq[nf][kk], s[mf][nf], 0, 0, 0);
      __builtin_amdgcn_s_setprio(0);
    }
    #pragma unroll
    for (int nf = 0; nf < 2; ++nf) {
      float mnew = m_run[nf];
      #pragma unroll
      for (int mf = 0; mf < 8; ++mf)
        #pragma unroll
        for (int j = 0; j < 4; ++j)
          mnew = fmaxf(mnew, s[mf][nf][j]);
      mnew = fmaxf(mnew, __shfl_xor(mnew, 16));
      mnew = fmaxf(mnew, __shfl_xor(mnew, 32));
      float fs = exp2f((m_run[nf] - mnew) * 1.44269504f);
      m_run[nf] = mnew;
      float rs = 0.0f;
      #pragma unroll
      for (int mf = 0; mf < 8; ++mf) {
        float4 mk = *(const float4*)(maskf + (size_t)bh * LLEN + lt * 128 + mf * 16 + 4 * g);
        #pragma unroll
        for (int j = 0; j < 4; ++j) {
          float p = exp2f((s[mf][nf][j] - mnew) * 1.44269504f) * ((const float*)&mk)[j];
          s[mf][nf][j] = p;
          rs += p;
        }
      }
      rs += __shfl_xor(rs, 16);
      rs += __shfl_xor(rs, 32);
      l_run[nf] = l_run[nf] * fs + rs;
      #pragma unroll
      for (int mf = 0; mf < 4; ++mf) acc_o[mf][nf] *= fs;
    }
    #pragma unroll
    for (int kk = 0; kk < 4; ++kk) {
      bf16x8 pb[2];
      #pragma unroll
      for (int nf = 0; nf < 2; ++nf)
        #pragma unroll
        for (int s8 = 0; s8 < 8; ++s8)
          pb[nf][s8] = (bf16)s[kk * 2 + (s8 >> 2)][nf][s8 & 3];
      #pragma unroll
      for (int mf = 0; mf < 4; ++mf) {
        int d = mf * 16 + c;
        uint32_t base = (uint32_t)(d * 256 + (kk * 32 + g * 4) * 2);
        uint32_t swzb = (uint32_t)((d & 7) << 4);
        bf16x4 lo = *(const bf16x4*)((char*)Vs + (base ^ swzb));
        bf16x4 hi = *(const bf16x4*)((char*)Vs + ((base + 32) ^ swzb));
        bf16x8 av = __builtin_shufflevector(lo, hi, 0, 1, 2, 3, 4, 5, 6, 7);
        __builtin_amdgcn_s_setprio(1);
        #pragma unroll
        for (int nf = 0; nf < 2; ++nf)
          acc_o[mf][nf] = __builtin_amdgcn_mfma_f32_16x16x32_bf16(av, pb[nf], acc_o[mf][nf], 0, 0, 0);
        __builtin_amdgcn_s_setprio(0);
      }
    }
    if (lt < 3) {
      __syncthreads();
      stage_kv(KH, VT, Ks, Vs, bh, lt + 1, t);
      __syncthreads();
    }
  }
  #pragma unroll
  for (int nf = 0; nf < 2; ++nf) {
    float inv = 1.0f / l_run[nf];
    int qq = q0 + w * 32 + nf * 16 + c;
    #pragma unroll
    for (int mf = 0; mf < 4; ++mf) {
      bf16x4 o;
      #pragma unroll
      for (int j = 0; j < 4; ++j) o[j] = (bf16)(acc_o[mf][nf][j] * inv);
      *(bf16x4*)(AO + ((size_t)(b * TQ + qq)) * DM + h * 64 + mf * 16 + 4 * g) = o;
    }
  }
}

extern "C" void kernel_launch(void* const* d_in, const int* in_sizes, int n_in,
                              void* d_out, int out_size, void* d_ws, size_t ws_size,
                              hipStream_t stream) {
  const float* q   = (const float*)d_in[0];
  const float* k   = (const float*)d_in[1];
  const float* v   = (const float*)d_in[2];
  const int*  smk  = (const int*)d_in[3];
  const float* w_q = (const float*)d_in[4];
  const float* b_q = (const float*)d_in[5];
  const float* w_k = (const float*)d_in[6];
  const float* b_k = (const float*)d_in[7];
  const float* w_v = (const float*)d_in[8];
  const float* b_v = (const float*)d_in[9];
  const float* w_o = (const float*)d_in[10];
  const float* b_o = (const float*)d_in[11];
  float* out = (float*)d_out;

  bf16* WS  = (bf16*)d_ws;
  bf16* WQ  = WS;
  bf16* WK  = WQ + (1u << 20);
  bf16* WV  = WK + (1u << 20);
  bf16* WO  = WV + (1u << 20);
  bf16* QB  = WO + (1u << 20);
  bf16* QP  = QB + (8u << 20);
  bf16* KH  = QP + (8u << 20);
  bf16* VTT = KH + (2u << 20);
  bf16* AO  = VTT + (2u << 20);
  float* MF = (float*)(AO + (8u << 20));

  prep_kernel<<<2048, 256, 0, stream>>>(q, w_q, w_k, w_v, w_o, smk, QB, WQ, WK, WV, WO, MF);
  gemm_bt_bias<true><<<512, 256, 0, stream>>>(QB, WQ, b_q, QP, 0.125f);
  kv_proj2<<<4096, 256, 0, stream>>>(k, v, WK, WV, b_k, b_v, KH, VTT);
  attn_kernel<<<1024, 256, 0, stream>>>(QP, KH, VTT, MF, AO);
  gemm_bt_bias<false><<<512, 256, 0, stream>>>(AO, WO, b_o, out, 1.0f);
}